// Round 2
// baseline (170.354 us; speedup 1.0000x reference)
//
#include <hip/hip_runtime.h>

#define BATCH 8192
#define HIST  50
#define REPR  512
#define N_EMB 100000
#define NPASS 4
#define SLICE (N_EMB / NPASS)   // 25000 rows = 51.2 MB per slice

// Slice-phased embedding-bag sum.
// Pass p gathers only indices in [p*SLICE, (p+1)*SLICE): the hot table
// footprint per pass is 51 MB << 256 MB L3, so the ~3.3x reuse per table row
// hits L3 instead of churning it. Pass 0 initializes out, later passes RMW.
// One batch row = 128 threads (one float4 slice each); 2 rows / 256-thr block.
template <bool FIRST>
__global__ __launch_bounds__(256) void embbag_pass_kernel(
    const int* __restrict__ target,      // [BATCH, HIST], -1 = sentinel
    const float* __restrict__ emb,       // [N_EMB, REPR]
    float* __restrict__ out,             // [BATCH, REPR]
    int lo, int hi)
{
    const int row  = blockIdx.x * 2 + (threadIdx.x >> 7);
    const int lane = threadIdx.x & 127;

    const int* t = target + row * HIST;
    const float* col = emb + (size_t)lane * 4;

    float4 acc = make_float4(0.f, 0.f, 0.f, 0.f);

#pragma unroll 5
    for (int j = 0; j < HIST; ++j) {
        const int idx = t[j];  // wave-uniform broadcast load
        // sentinel (-1) is always < lo since lo >= 0
        if (idx >= lo && idx < hi) {
            const float4 v =
                *reinterpret_cast<const float4*>(col + (size_t)idx * REPR);
            acc.x += v.x;
            acc.y += v.y;
            acc.z += v.z;
            acc.w += v.w;
        }
    }

    float4* o = reinterpret_cast<float4*>(out + (size_t)row * REPR + (size_t)lane * 4);
    if (!FIRST) {
        const float4 prev = *o;
        acc.x += prev.x;
        acc.y += prev.y;
        acc.z += prev.z;
        acc.w += prev.w;
    }
    *o = acc;
}

extern "C" void kernel_launch(void* const* d_in, const int* in_sizes, int n_in,
                              void* d_out, int out_size, void* d_ws, size_t ws_size,
                              hipStream_t stream) {
    const int*   target = (const int*)d_in[0];
    const float* emb    = (const float*)d_in[1];
    float*       out    = (float*)d_out;

    dim3 grid(BATCH / 2);
    dim3 block(256);

    embbag_pass_kernel<true><<<grid, block, 0, stream>>>(
        target, emb, out, 0, SLICE);
    for (int p = 1; p < NPASS; ++p) {
        embbag_pass_kernel<false><<<grid, block, 0, stream>>>(
            target, emb, out, p * SLICE, (p + 1) * SLICE);
    }
}

// Round 3
// 99.570 us; speedup vs baseline: 1.7109x; 1.7109x over previous
//
#include <hip/hip_runtime.h>

#define BATCH 8192
#define HIST  50
#define REPR  512
#define CH    10   // gathers kept in flight per wave; 5 chunks cover HIST=50

// One batch row = 128 threads, each owning one float4 (16 B) of the 512-dim
// embedding; 2 rows per 256-thread block. Inner loop is batched CH-deep:
// issue CH independent float4 gathers (sentinels redirected to row 0, which
// stays cache-hot, with weight 0) before consuming any -> ~CH loads in
// flight per wave instead of ~2 (the round-1 kernel had only 12 VGPRs).
__global__ __launch_bounds__(256) void embbag_sum_kernel(
    const int* __restrict__ target,      // [BATCH, HIST], -1 = sentinel
    const float* __restrict__ emb,       // [N_EMB, REPR]
    float* __restrict__ out)             // [BATCH, REPR]
{
    const int row  = blockIdx.x * 2 + (threadIdx.x >> 7);
    const int lane = threadIdx.x & 127;

    const int* t = target + row * HIST;
    const float* col = emb + (size_t)lane * 4;

    float4 acc = make_float4(0.f, 0.f, 0.f, 0.f);

    for (int j0 = 0; j0 < HIST; j0 += CH) {
        int   idx[CH];   // wave-uniform -> compiler can scalarize
        float w[CH];
        float4 v[CH];

#pragma unroll
        for (int k = 0; k < CH; ++k) {
            const int ix = t[j0 + k];
            w[k]   = (ix >= 0) ? 1.0f : 0.0f;
            idx[k] = (ix >= 0) ? ix : 0;
        }

#pragma unroll
        for (int k = 0; k < CH; ++k) {
            v[k] = *reinterpret_cast<const float4*>(col + (size_t)idx[k] * REPR);
        }

#pragma unroll
        for (int k = 0; k < CH; ++k) {
            acc.x = fmaf(v[k].x, w[k], acc.x);
            acc.y = fmaf(v[k].y, w[k], acc.y);
            acc.z = fmaf(v[k].z, w[k], acc.z);
            acc.w = fmaf(v[k].w, w[k], acc.w);
        }
    }

    *reinterpret_cast<float4*>(out + (size_t)row * REPR + (size_t)lane * 4) = acc;
}

extern "C" void kernel_launch(void* const* d_in, const int* in_sizes, int n_in,
                              void* d_out, int out_size, void* d_ws, size_t ws_size,
                              hipStream_t stream) {
    const int*   target = (const int*)d_in[0];
    const float* emb    = (const float*)d_in[1];
    float*       out    = (float*)d_out;

    dim3 grid(BATCH / 2);
    dim3 block(256);
    embbag_sum_kernel<<<grid, block, 0, stream>>>(target, emb, out);
}